// Round 1
// baseline (607.660 us; speedup 1.0000x reference)
//
#include <hip/hip_runtime.h>
#include <math.h>

#define BB 64
#define TT 2048
#define DD 768
#define PP 1024
#define KK 8
#define TSPLIT 32
#define TCHUNK (TT / TSPLIT)   // 64
#define D4 (DD / 4)            // 192

// ---------------------------------------------------------------------------
// ws layout (4-byte units) — no harness-zero dependency; counts zeroed by K1:
//   pmax   : float[BB*TSPLIT*DD] = 1572864  (6 MB, per-chunk token-max partials)
//   counts : int  [PP]           = 1024
//   sim    : float[BB*PP]        = 65536
//   major  : int  [KK]           = 8
//   xproj  : float[BB*DD]        = 49152
// ---------------------------------------------------------------------------

__device__ __forceinline__ float wave_sum(float v) {
    for (int off = 32; off > 0; off >>= 1) v += __shfl_down(v, off, 64);
    return v;
}

// order-preserving float->uint map (monotone for all non-NaN floats)
__device__ __forceinline__ unsigned int fmap(float f) {
    unsigned int b = __float_as_uint(f);
    return (b & 0x80000000u) ? ~b : (b | 0x80000000u);
}

// K1: single-pass token-max partials (non-atomic) + zero counts.
// grid (TSPLIT, BB), block 192.  Reads 402 MB (the HBM-bound pass).
__global__ __launch_bounds__(192) void k_maxpart(const float* __restrict__ x,
                                                 float* __restrict__ pmax,
                                                 int* __restrict__ counts) {
    const int chunk = blockIdx.x, b = blockIdx.y, d4 = threadIdx.x;
    if (chunk == 0 && b == 0)
        for (int i = threadIdx.x; i < PP; i += 192) counts[i] = 0;
    const float4* x4 = (const float4*)x;
    size_t base = ((size_t)b * TT + (size_t)chunk * TCHUNK) * D4 + d4;
    float4 m = make_float4(-INFINITY, -INFINITY, -INFINITY, -INFINITY);
    #pragma unroll 8
    for (int t = 0; t < TCHUNK; ++t) {
        float4 v = x4[base + (size_t)t * D4];
        m.x = fmaxf(m.x, v.x); m.y = fmaxf(m.y, v.y);
        m.z = fmaxf(m.z, v.z); m.w = fmaxf(m.w, v.w);
    }
    float4* dst = (float4*)pmax + ((size_t)b * TSPLIT + chunk) * D4 + d4;
    *dst = m;  // coalesced, non-atomic; L2-resident (6 MB total)
}

// K2: reduce partial maxes -> xm (LDS), then x_proj = xm @ W^T.
// grid (4, BB), block 256 (4 waves, 48 outputs each).
__global__ __launch_bounds__(256) void k_proj(const float* __restrict__ pmax,
                                              const float* __restrict__ W,
                                              float* __restrict__ xproj) {
    __shared__ float xm[DD];
    const int b = blockIdx.y;
    const int o0 = blockIdx.x * 192;
    if (threadIdx.x < D4) {
        const float4* p4 = (const float4*)pmax + (size_t)b * TSPLIT * D4 + threadIdx.x;
        float4 m = p4[0];
        #pragma unroll
        for (int c = 1; c < TSPLIT; ++c) {
            float4 v = p4[(size_t)c * D4];
            m.x = fmaxf(m.x, v.x); m.y = fmaxf(m.y, v.y);
            m.z = fmaxf(m.z, v.z); m.w = fmaxf(m.w, v.w);
        }
        ((float4*)xm)[threadIdx.x] = m;
    }
    __syncthreads();
    const int wave = threadIdx.x >> 6, lane = threadIdx.x & 63;
    const float4* xm4 = (const float4*)xm;
    for (int k = 0; k < 48; ++k) {
        const int o = o0 + 4 * k + wave;
        const float4* w4 = (const float4*)(W + (size_t)o * DD);
        float acc = 0.f;
        #pragma unroll
        for (int j = 0; j < 3; ++j) {
            float4 a = xm4[j * 64 + lane];
            float4 w = w4[j * 64 + lane];
            acc += a.x * w.x + a.y * w.y + a.z * w.z + a.w * w.w;
        }
        acc = wave_sum(acc);
        if (lane == 0) xproj[b * DD + o] = acc;
    }
}

// K3: sim[b,p] = dot(xproj[b], prompt[p]) * rsqrt(||xproj[b]||^2) * rsqrt(||prompt[p]||^2).
// xs computed in-block from the LDS copy (no xss atomics); pscale computed inline
// from the same prompt loads (no separate pscale pass).
// grid (8, BB), block 256 (4 waves, 32 p's each).
__global__ __launch_bounds__(256) void k_sim(const float* __restrict__ xproj,
                                             const float* __restrict__ prompt,
                                             float* __restrict__ sim) {
    __shared__ float xp[DD];
    __shared__ float wss[4];
    const int b = blockIdx.y;
    const int p0 = blockIdx.x * 128;
    float ssl = 0.f;
    for (int i = threadIdx.x; i < DD; i += 256) {
        float v = xproj[b * DD + i];
        xp[i] = v;
        ssl += v * v;
    }
    ssl = wave_sum(ssl);
    const int wave = threadIdx.x >> 6, lane = threadIdx.x & 63;
    if (lane == 0) wss[wave] = ssl;
    __syncthreads();
    const float xs = 1.0f / sqrtf(fmaxf(wss[0] + wss[1] + wss[2] + wss[3], 1e-12f));
    const float4* xp4 = (const float4*)xp;
    for (int k = 0; k < 32; ++k) {
        const int p = p0 + 4 * k + wave;
        const float4* pr4 = (const float4*)(prompt + (size_t)p * DD);
        float acc = 0.f, ps = 0.f;
        #pragma unroll
        for (int j = 0; j < 3; ++j) {
            float4 a = xp4[j * 64 + lane];
            float4 v = pr4[j * 64 + lane];
            acc += a.x * v.x + a.y * v.y + a.z * v.z + a.w * v.w;
            ps  += v.x * v.x + v.y * v.y + v.z * v.z + v.w * v.w;
        }
        acc = wave_sum(acc);
        ps  = wave_sum(ps);
        if (lane == 0)
            sim[b * PP + p] = acc * xs * (1.0f / sqrtf(fmaxf(ps, 1e-12f)));
    }
}

// K4: per-row top-8 (ties -> lowest index), then bincount via atomics.  grid BB, block 256.
__global__ __launch_bounds__(256) void k_topk_rows(const float* __restrict__ sim,
                                                   int* __restrict__ counts) {
    __shared__ unsigned long long keys[PP];
    __shared__ unsigned long long wmax[4];
    __shared__ int sel[KK];
    const int b = blockIdx.x, tid = threadIdx.x;
    const int lane = tid & 63, wave = tid >> 6;
    for (int p = tid; p < PP; p += 256) {
        unsigned long long k = ((unsigned long long)fmap(sim[b * PP + p]) << 32)
                             | (unsigned int)(PP - 1 - p);
        keys[p] = k;
    }
    __syncthreads();
    for (int it = 0; it < KK; ++it) {
        unsigned long long mk = 0;
        for (int p = tid; p < PP; p += 256) {
            unsigned long long v = keys[p];
            if (v > mk) mk = v;
        }
        for (int off = 32; off > 0; off >>= 1) {
            unsigned long long o = __shfl_down(mk, off, 64);
            if (o > mk) mk = o;
        }
        if (lane == 0) wmax[wave] = mk;
        __syncthreads();
        if (tid == 0) {
            unsigned long long m = wmax[0];
            for (int w = 1; w < 4; ++w) if (wmax[w] > m) m = wmax[w];
            int p = PP - 1 - (int)(m & 0xFFFFFFFFu);
            sel[it] = p;
            keys[p] = 0ull;
        }
        __syncthreads();
    }
    if (tid < KK) atomicAdd(&counts[sel[tid]], 1);
}

// K5: top-8 of counts (ties -> lowest id), ordered.  grid 1, block 256.
__global__ __launch_bounds__(256) void k_topk_counts(const int* __restrict__ counts,
                                                     int* __restrict__ major) {
    __shared__ unsigned long long keys[PP];
    __shared__ unsigned long long wmax[4];
    const int tid = threadIdx.x;
    const int lane = tid & 63, wave = tid >> 6;
    for (int p = tid; p < PP; p += 256)
        keys[p] = ((unsigned long long)(unsigned int)counts[p] << 32)
                | (unsigned int)(PP - 1 - p);
    __syncthreads();
    for (int it = 0; it < KK; ++it) {
        unsigned long long mk = 0;
        for (int p = tid; p < PP; p += 256) {
            unsigned long long v = keys[p];
            if (v > mk) mk = v;
        }
        for (int off = 32; off > 0; off >>= 1) {
            unsigned long long o = __shfl_down(mk, off, 64);
            if (o > mk) mk = o;
        }
        if (lane == 0) wmax[wave] = mk;
        __syncthreads();
        if (tid == 0) {
            unsigned long long m = wmax[0];
            for (int w = 1; w < 4; ++w) if (wmax[w] > m) m = wmax[w];
            int p = PP - 1 - (int)(m & 0xFFFFFFFFu);
            major[it] = p;
            keys[p] = 0ull;
        }
        __syncthreads();
    }
}

// K6: outputs.  d_out[0] = reduce_sim, d_out[1..] = batched_prompt [BB][KK][DD].
// grid BB*KK + 1, block 192.
__global__ __launch_bounds__(192) void k_out(const float* __restrict__ prompt,
                                             const float* __restrict__ sim,
                                             const int* __restrict__ major,
                                             float* __restrict__ out) {
    if (blockIdx.x < BB * KK) {
        const int b = blockIdx.x >> 3, k = blockIdx.x & 7;
        const int id = major[k];
        const float* src = prompt + (size_t)id * DD;
        float* dst = out + 1 + ((size_t)(b * KK + k)) * DD;
        for (int i = threadIdx.x; i < DD; i += 192) dst[i] = src[i];
    } else {
        __shared__ float wsum[3];
        float s = 0.f;
        for (int i = threadIdx.x; i < BB * KK; i += 192) {
            const int b = i >> 3, k = i & 7;
            s += sim[b * PP + major[k]];
        }
        s = wave_sum(s);
        const int lane = threadIdx.x & 63, wave = threadIdx.x / 64;
        if (lane == 0) wsum[wave] = s;
        __syncthreads();
        if (threadIdx.x == 0) out[0] = (wsum[0] + wsum[1] + wsum[2]) / (float)BB;
    }
}

extern "C" void kernel_launch(void* const* d_in, const int* in_sizes, int n_in,
                              void* d_out, int out_size, void* d_ws, size_t ws_size,
                              hipStream_t stream) {
    const float* x      = (const float*)d_in[0];   // [64,2048,768]
    const float* prompt = (const float*)d_in[1];   // [1024,768]
    const float* W      = (const float*)d_in[2];   // [768,768]
    float* out = (float*)d_out;

    float* ws     = (float*)d_ws;
    float* pmax   = ws;                                        // BB*TSPLIT*DD
    int*   counts = (int*)(pmax + (size_t)BB * TSPLIT * DD);   // PP
    float* sim    = (float*)(counts + PP);                     // BB*PP
    int*   major  = (int*)(sim + (size_t)BB * PP);             // KK
    float* xproj  = (float*)(major + KK);                      // BB*DD

    k_maxpart<<<dim3(TSPLIT, BB), 192, 0, stream>>>(x, pmax, counts);
    k_proj<<<dim3(4, BB), 256, 0, stream>>>(pmax, W, xproj);
    k_sim<<<dim3(8, BB), 256, 0, stream>>>(xproj, prompt, sim);
    k_topk_rows<<<BB, 256, 0, stream>>>(sim, counts);
    k_topk_counts<<<1, 256, 0, stream>>>(counts, major);
    k_out<<<BB * KK + 1, 192, 0, stream>>>(prompt, sim, major, out);
}